// Round 7
// baseline (835.535 us; speedup 1.0000x reference)
//
#include <hip/hip_runtime.h>
#include <hip/hip_bf16.h>
#include <stdint.h>
#include <stdio.h>

// Problem geometry (fixed by the reference)
#define M_DIM 8192    // 4*2048
#define K_DIM 4096    // IN_FEATURES
#define N_DIM 11008   // OUT_FEATURES

// 256^2 8-phase template (m201 structure)
#define BM 256
#define BN 256
#define BK 64
#define NT (K_DIM / BK)           // 64 K-tiles (power of 2 -> & wrap ok)
#define TILES_M (M_DIM / BM)      // 32
#define TILES_N (N_DIM / BN)      // 43
#define NWG (TILES_M * TILES_N)   // 1376 (%8==0 -> simple XCD swizzle bijective)

typedef __bf16 bf16x8 __attribute__((ext_vector_type(8)));
typedef float f32x4 __attribute__((ext_vector_type(4)));

__device__ __constant__ float kFp4Code[16] = {
    0.0f,           0.0052083333f,  0.6666666666f, 1.0f,
    0.3333333333f,  0.5f,           0.1666666666f, 0.25f,
    -0.0f,          -0.0052083333f, -0.6666666666f, -1.0f,
    -0.3333333333f, -0.5f,          -0.1666666666f, -0.25f
};

// ---------------------------------------------------------------------------
// Kernel 1: FP4 dequant -> bf16 W [N_DIM][K_DIM]
// ---------------------------------------------------------------------------
__global__ __launch_bounds__(256) void fp4_dequant_kernel(
    const int* __restrict__ codes, const float* __restrict__ absmax,
    __hip_bfloat16* __restrict__ w)
{
    __shared__ float lut[16];
    if (threadIdx.x < 16) lut[threadIdx.x] = kFp4Code[threadIdx.x];
    __syncthreads();

    const int t = blockIdx.x * 256 + threadIdx.x;  // < 5,636,096
    const int4* cp = (const int4*)codes;
    const int4 c0 = cp[2 * t];
    const int4 c1 = cp[2 * t + 1];
    const float am = absmax[t >> 3];

    union { int4 v; __hip_bfloat16 h[8]; } u;
    u.h[0] = __float2bfloat16(lut[c0.x & 15] * am);
    u.h[1] = __float2bfloat16(lut[c0.y & 15] * am);
    u.h[2] = __float2bfloat16(lut[c0.z & 15] * am);
    u.h[3] = __float2bfloat16(lut[c0.w & 15] * am);
    u.h[4] = __float2bfloat16(lut[c1.x & 15] * am);
    u.h[5] = __float2bfloat16(lut[c1.y & 15] * am);
    u.h[6] = __float2bfloat16(lut[c1.z & 15] * am);
    u.h[7] = __float2bfloat16(lut[c1.w & 15] * am);
    ((int4*)w)[t] = u.v;
}

// ---------------------------------------------------------------------------
// Kernel 2: x fp32 -> bf16  [M_DIM][K_DIM]
// ---------------------------------------------------------------------------
__global__ __launch_bounds__(256) void f32_to_bf16_kernel(
    const float* __restrict__ x, __hip_bfloat16* __restrict__ y)
{
    const int t = blockIdx.x * 256 + threadIdx.x;  // < 4,194,304
    const float4* xp = (const float4*)x;
    const float4 a = xp[2 * t];
    const float4 b = xp[2 * t + 1];
    union { int4 v; __hip_bfloat16 h[8]; } u;
    u.h[0] = __float2bfloat16(a.x);
    u.h[1] = __float2bfloat16(a.y);
    u.h[2] = __float2bfloat16(a.z);
    u.h[3] = __float2bfloat16(a.w);
    u.h[4] = __float2bfloat16(b.x);
    u.h[5] = __float2bfloat16(b.y);
    u.h[6] = __float2bfloat16(b.z);
    u.h[7] = __float2bfloat16(b.w);
    ((int4*)y)[t] = u.v;
}

// ---------------------------------------------------------------------------
// Kernel 3: bf16 GEMM, C = A * B^T + bias   (256x256 tile, 8-phase schedule)
//
// Round-7 change vs round-6: REMOVE the explicit `s_waitcnt lgkmcnt(0)` asm
// before each MFMA cluster. Rounds 4-6 PMC arithmetic: 48 ds_read_b128/phase
// x 12 cyc = 576 cyc LDS-pipe + 620 cyc MFMA, and the blanket lgkm drain
// (asm "memory" clobber) SERIALIZED them -> 1250 cyc/phase, MfmaUtil 41-43%.
// The ds_reads here are compiler-visible loads with real register deps, so
// hipcc emits fine-grained lgkmcnt(N) per consuming MFMA (m97 finding) and
// read completion pipelines under the MFMA cluster. Reads are issued
// ks0-group first and the MFMA loop is ks-outer, so the first 6 reads feed 8
// independent MFMAs (acc-chain distance 8). Safety unchanged: every phase's
// reads are fully consumed by that phase's own MFMAs -> data-dependence
// forces completion before barrier#2 -> region-overwrite ledger identical to
// rounds 5/6. Barrier / stage / per-tile-vmcnt skeleton: byte-identical.
//
// LDS (128 KiB): 2 dbuf x { A-lo@0, A-hi@16384, B-lo@32768, B-hi@49152 },
// buffer b at b*65536. XOR involution swizzle (round-2-proven, 0 conflicts):
// LDS slot (row,c) holds global chunk (row, c^(row&7)); gload_lds dest LINEAR.
// Stage stream (per tile t, buf=t&1): P0: A-hi(t+1); P1: A-lo(t+2);
// P2: B-lo(t+2); P3: B-hi(t+2) + the ONE vmcnt(6) per tile.
// ---------------------------------------------------------------------------
#define STAGE(gbase, eoff, loff)                                              \
    __builtin_amdgcn_global_load_lds(                                         \
        (const __attribute__((address_space(1))) void*)((gbase) + (eoff)),    \
        (__attribute__((address_space(3))) void*)(lds + (loff)), 16, 0, 0)

__device__ __forceinline__ void mfma_quad(
    f32x4 (&accq)[4][2], bf16x8 (&av)[4][2], bf16x8 (&bv)[2][2])
{
    __builtin_amdgcn_s_setprio(1);
#pragma unroll
    for (int ks = 0; ks < 2; ++ks)        // ks-outer: 8 independent MFMAs per
#pragma unroll
        for (int m = 0; m < 4; ++m)       // group; acc dependence distance 8
#pragma unroll
            for (int n = 0; n < 2; ++n)
                accq[m][n] = __builtin_amdgcn_mfma_f32_16x16x32_bf16(
                    av[m][ks], bv[n][ks], accq[m][n], 0, 0, 0);
    __builtin_amdgcn_s_setprio(0);
}

template<int BUF>
__device__ __forceinline__ void tile_body(
    int t, f32x4 (&acc)[4][4][2],
    const __hip_bfloat16* __restrict__ A, const __hip_bfloat16* __restrict__ B,
    char* lds,
    const int (&sA_lo)[2], const int (&sA_hi)[2],
    const int (&sB_lo)[2], const int (&sB_hi)[2],
    int dst0, int dst1,
    const char* pA0, const char* pA1, const char* pB0, const char* pB1)
{
    constexpr int LB  = BUF * 65536;         // this tile's buffer
    constexpr int LB1 = (BUF ^ 1) * 65536;   // (t+1)'s buffer
    const int koff1 = ((t + 1) & (NT - 1)) * 64;   // wave-uniform (SALU)
    const int koff2 = ((t + 2) & (NT - 1)) * 64;

    bf16x8 avLo[4][2], avHi[4][2], bvLo[2][2], bvHi[2][2];

    // ---- P0: Q(0,0): read A-lo + B-lo (12 b128, ks0 group first);
    //      stage A-hi(t+1) ----
#pragma unroll
    for (int n = 0; n < 2; ++n) bvLo[n][0] = *(const bf16x8*)(pB0 + LB + n * 2048);
#pragma unroll
    for (int m = 0; m < 4; ++m) avLo[m][0] = *(const bf16x8*)(pA0 + LB + m * 2048);
#pragma unroll
    for (int n = 0; n < 2; ++n) bvLo[n][1] = *(const bf16x8*)(pB1 + LB + n * 2048);
#pragma unroll
    for (int m = 0; m < 4; ++m) avLo[m][1] = *(const bf16x8*)(pA1 + LB + m * 2048);
    STAGE(A, sA_hi[0] + koff1, LB1 + 16384 + dst0);
    STAGE(A, sA_hi[1] + koff1, LB1 + 16384 + dst1);
    __builtin_amdgcn_s_barrier();
    mfma_quad(acc[0], avLo, bvLo);        // compiler fine-grained lgkm waits
    __builtin_amdgcn_s_barrier();

    // ---- P1: Q(0,1): read B-hi (4); stage A-lo(t+2); A-lo held ----
#pragma unroll
    for (int n = 0; n < 2; ++n) bvHi[n][0] = *(const bf16x8*)(pB0 + LB + 16384 + n * 2048);
#pragma unroll
    for (int n = 0; n < 2; ++n) bvHi[n][1] = *(const bf16x8*)(pB1 + LB + 16384 + n * 2048);
    STAGE(A, sA_lo[0] + koff2, LB + dst0);
    STAGE(A, sA_lo[1] + koff2, LB + dst1);
    __builtin_amdgcn_s_barrier();
    mfma_quad(acc[1], avLo, bvHi);
    __builtin_amdgcn_s_barrier();

    // ---- P2: Q(1,1): read A-hi (8); stage B-lo(t+2); B-hi held ----
#pragma unroll
    for (int m = 0; m < 4; ++m) avHi[m][0] = *(const bf16x8*)(pA0 + LB + 16384 + m * 2048);
#pragma unroll
    for (int m = 0; m < 4; ++m) avHi[m][1] = *(const bf16x8*)(pA1 + LB + 16384 + m * 2048);
    STAGE(B, sB_lo[0] + koff2, LB + 32768 + dst0);
    STAGE(B, sB_lo[1] + koff2, LB + 32768 + dst1);
    __builtin_amdgcn_s_barrier();
    mfma_quad(acc[2], avHi, bvHi);
    __builtin_amdgcn_s_barrier();

    // ---- P3: Q(1,0): no ds_read (A-hi, B-lo held); stage B-hi(t+2);
    //      the ONE vmcnt per tile: 3 newest halves stay in flight ----
    STAGE(B, sB_hi[0] + koff2, LB + 49152 + dst0);
    STAGE(B, sB_hi[1] + koff2, LB + 49152 + dst1);
    asm volatile("s_waitcnt vmcnt(6)" ::: "memory");
    __builtin_amdgcn_s_barrier();
    mfma_quad(acc[3], avHi, bvLo);
    __builtin_amdgcn_s_barrier();
}

__global__ __launch_bounds__(512, 2) void gemm_bf16_8phase(
    const __hip_bfloat16* __restrict__ A, const __hip_bfloat16* __restrict__ B,
    const float* __restrict__ bias, float* __restrict__ C)
{
    extern __shared__ char lds[];  // 131072 B

    const int tid = threadIdx.x;
    const int lane = tid & 63;
    const int wid = tid >> 6;       // 0..7
    const int wr = wid >> 2;        // 0..1 (M split)
    const int wc = wid & 3;         // 0..3 (N split)
    const int l15 = lane & 15;
    const int kgrp = lane >> 4;

    // XCD-aware bijective swizzle; consecutive same-XCD blocks share tile_n
    // -> 2 MB B panel stays L2-resident.
    const int wg = blockIdx.x;
    const int swz = (wg & 7) * (NWG / 8) + (wg >> 3);
    const int tile_m = swz % TILES_M;
    const int tile_n = swz / TILES_M;
    const int m0 = tile_m * BM;
    const int n0 = tile_n * BN;

    // ---- Precomputed stage-source element offsets (per lane, once) ----
    int sA_lo[2], sA_hi[2], sB_lo[2], sB_hi[2];
#pragma unroll
    for (int c = 0; c < 2; ++c) {
        const int idx = c * 512 + tid;          // 0..1023 chunk id (linear LDS)
        const int row = idx >> 3;               // 0..127
        const int scol = (idx & 7) ^ (row & 7); // pre-swizzled source chunk
        sA_lo[c] = (m0 + row) * K_DIM + scol * 8;
        sA_hi[c] = sA_lo[c] + 128 * K_DIM;
        sB_lo[c] = (n0 + row) * K_DIM + scol * 8;
        sB_hi[c] = sB_lo[c] + 128 * K_DIM;
    }
    const int dst0 = wid * 1024;          // (c*512 + wid*64)*16, c=0
    const int dst1 = 8192 + wid * 1024;   // c=1

    // ---- Precomputed fragment-read base pointers (buf0; buf1 = +65536) ----
    // Full addr = base + {A-hi/B-hi: +16384} + m|n * 2048  (compile-time imms)
    const int xlo = l15 & 7;
    const char* pA0 = lds + (wr * 64 + l15) * 128 + ((kgrp) ^ xlo) * 16;
    const char* pA1 = lds + (wr * 64 + l15) * 128 + ((4 + kgrp) ^ xlo) * 16;
    const char* pB0 = lds + 32768 + (wc * 32 + l15) * 128 + ((kgrp) ^ xlo) * 16;
    const char* pB1 = lds + 32768 + (wc * 32 + l15) * 128 + ((4 + kgrp) ^ xlo) * 16;

    // acc quadrants: 0=(0,0) 1=(0,1) 2=(1,1) 3=(1,0)  (mq,nq)
    f32x4 acc[4][4][2];
#pragma unroll
    for (int q = 0; q < 4; ++q)
#pragma unroll
        for (int m = 0; m < 4; ++m)
#pragma unroll
            for (int n = 0; n < 2; ++n)
                acc[q][m][n] = (f32x4){0.f, 0.f, 0.f, 0.f};

    // Prologue: 7 halves, same issue order as rounds 5/6:
    // A-lo(0), B-lo(0), B-hi(0), A-hi(0), A-lo(1), B-lo(1), B-hi(1)
    STAGE(A, sA_lo[0], dst0);                 STAGE(A, sA_lo[1], dst1);
    STAGE(B, sB_lo[0], 32768 + dst0);         STAGE(B, sB_lo[1], 32768 + dst1);
    STAGE(B, sB_hi[0], 49152 + dst0);         STAGE(B, sB_hi[1], 49152 + dst1);
    STAGE(A, sA_hi[0], 16384 + dst0);         STAGE(A, sA_hi[1], 16384 + dst1);
    STAGE(A, sA_lo[0] + 64, 65536 + dst0);    STAGE(A, sA_lo[1] + 64, 65536 + dst1);
    STAGE(B, sB_lo[0] + 64, 98304 + dst0);    STAGE(B, sB_lo[1] + 64, 98304 + dst1);
    STAGE(B, sB_hi[0] + 64, 114688 + dst0);   STAGE(B, sB_hi[1] + 64, 114688 + dst1);
    asm volatile("s_waitcnt vmcnt(6)" ::: "memory"); // tile-0's 4 halves landed
    __builtin_amdgcn_s_barrier();

    for (int t = 0; t < NT; t += 2) {
        tile_body<0>(t,     acc, A, B, lds, sA_lo, sA_hi, sB_lo, sB_hi,
                     dst0, dst1, pA0, pA1, pB0, pB1);
        tile_body<1>(t + 1, acc, A, B, lds, sA_lo, sA_hi, sB_lo, sB_hi,
                     dst0, dst1, pA0, pA1, pB0, pB1);
    }

    // Epilogue (C/D layout: col = lane&15, row = (lane>>4)*4 + reg).
    // Nontemporal: C written once, never re-read -> don't churn L3.
#pragma unroll
    for (int q = 0; q < 4; ++q) {
        const int mqe = q >> 1;
        const int nqe = (q == 1 || q == 2) ? 1 : 0;
#pragma unroll
        for (int n = 0; n < 2; ++n) {
            const int col = n0 + nqe * 128 + wc * 32 + n * 16 + l15;
            const float bval = bias[col];
#pragma unroll
            for (int m = 0; m < 4; ++m) {
                const int row = m0 + mqe * 128 + wr * 64 + m * 16 + kgrp * 4;
#pragma unroll
                for (int r = 0; r < 4; ++r)
                    __builtin_nontemporal_store(acc[q][m][n][r] + bval,
                        &C[(size_t)(row + r) * N_DIM + col]);
            }
        }
    }
}

// ---------------------------------------------------------------------------
extern "C" void kernel_launch(void* const* d_in, const int* in_sizes, int n_in,
                              void* d_out, int out_size, void* d_ws, size_t ws_size,
                              hipStream_t stream)
{
    const float* x      = (const float*)d_in[0];  // [4,2048,4096] f32
    const int*   codes  = (const int*)d_in[1];    // [704512,64] i32
    const float* absmax = (const float*)d_in[2];  // [704512] f32
    const float* bias   = (const float*)d_in[3];  // [11008] f32
    float* out = (float*)d_out;                   // [4,2048,11008] f32

    const size_t w_bytes = (size_t)N_DIM * K_DIM * sizeof(__hip_bfloat16);
    const size_t x_bytes = (size_t)M_DIM * K_DIM * sizeof(__hip_bfloat16);
    if (ws_size < w_bytes + x_bytes) {
        fprintf(stderr, "kernel_launch: ws_size=%zu < needed %zu\n",
                ws_size, w_bytes + x_bytes);
        return;
    }
    __hip_bfloat16* wbf = (__hip_bfloat16*)d_ws;
    __hip_bfloat16* xbf = (__hip_bfloat16*)((char*)d_ws + w_bytes);

    // Allow 128 KiB dynamic LDS (idempotent host-side call; capture-safe).
    hipFuncSetAttribute((const void*)gemm_bf16_8phase,
                        hipFuncAttributeMaxDynamicSharedMemorySize, 131072);

    fp4_dequant_kernel<<<dim3(22016), dim3(256), 0, stream>>>(codes, absmax, wbf);
    f32_to_bf16_kernel<<<dim3(16384), dim3(256), 0, stream>>>(x, xbf);
    gemm_bf16_8phase<<<dim3(NWG), dim3(512), 131072, stream>>>(xbf, wbf, bias, out);
}

// Round 8
// 832.240 us; speedup vs baseline: 1.0040x; 1.0040x over previous
//
#include <hip/hip_runtime.h>
#include <hip/hip_bf16.h>
#include <stdint.h>
#include <stdio.h>

// Problem geometry (fixed by the reference)
#define M_DIM 8192    // 4*2048
#define K_DIM 4096    // IN_FEATURES
#define N_DIM 11008   // OUT_FEATURES

// 256^2 8-phase template (m201 structure)
#define BM 256
#define BN 256
#define BK 64
#define NT (K_DIM / BK)           // 64 K-tiles (power of 2 -> & wrap ok)
#define TILES_M (M_DIM / BM)      // 32
#define TILES_N (N_DIM / BN)      // 43
#define NWG (TILES_M * TILES_N)   // 1376 (%8==0 -> simple XCD swizzle bijective)

typedef __bf16 bf16x8 __attribute__((ext_vector_type(8)));
typedef float f32x4 __attribute__((ext_vector_type(4)));

__device__ __constant__ float kFp4Code[16] = {
    0.0f,           0.0052083333f,  0.6666666666f, 1.0f,
    0.3333333333f,  0.5f,           0.1666666666f, 0.25f,
    -0.0f,          -0.0052083333f, -0.6666666666f, -1.0f,
    -0.3333333333f, -0.5f,          -0.1666666666f, -0.25f
};

// ---------------------------------------------------------------------------
// Kernel 1: FP4 dequant -> bf16 W [N_DIM][K_DIM]
// ---------------------------------------------------------------------------
__global__ __launch_bounds__(256) void fp4_dequant_kernel(
    const int* __restrict__ codes, const float* __restrict__ absmax,
    __hip_bfloat16* __restrict__ w)
{
    __shared__ float lut[16];
    if (threadIdx.x < 16) lut[threadIdx.x] = kFp4Code[threadIdx.x];
    __syncthreads();

    const int t = blockIdx.x * 256 + threadIdx.x;  // < 5,636,096
    const int4* cp = (const int4*)codes;
    const int4 c0 = cp[2 * t];
    const int4 c1 = cp[2 * t + 1];
    const float am = absmax[t >> 3];

    union { int4 v; __hip_bfloat16 h[8]; } u;
    u.h[0] = __float2bfloat16(lut[c0.x & 15] * am);
    u.h[1] = __float2bfloat16(lut[c0.y & 15] * am);
    u.h[2] = __float2bfloat16(lut[c0.z & 15] * am);
    u.h[3] = __float2bfloat16(lut[c0.w & 15] * am);
    u.h[4] = __float2bfloat16(lut[c1.x & 15] * am);
    u.h[5] = __float2bfloat16(lut[c1.y & 15] * am);
    u.h[6] = __float2bfloat16(lut[c1.z & 15] * am);
    u.h[7] = __float2bfloat16(lut[c1.w & 15] * am);
    ((int4*)w)[t] = u.v;
}

// ---------------------------------------------------------------------------
// Kernel 2: x fp32 -> bf16  [M_DIM][K_DIM]
// ---------------------------------------------------------------------------
__global__ __launch_bounds__(256) void f32_to_bf16_kernel(
    const float* __restrict__ x, __hip_bfloat16* __restrict__ y)
{
    const int t = blockIdx.x * 256 + threadIdx.x;  // < 4,194,304
    const float4* xp = (const float4*)x;
    const float4 a = xp[2 * t];
    const float4 b = xp[2 * t + 1];
    union { int4 v; __hip_bfloat16 h[8]; } u;
    u.h[0] = __float2bfloat16(a.x);
    u.h[1] = __float2bfloat16(a.y);
    u.h[2] = __float2bfloat16(a.z);
    u.h[3] = __float2bfloat16(a.w);
    u.h[4] = __float2bfloat16(b.x);
    u.h[5] = __float2bfloat16(b.y);
    u.h[6] = __float2bfloat16(b.z);
    u.h[7] = __float2bfloat16(b.w);
    ((int4*)y)[t] = u.v;
}

// ---------------------------------------------------------------------------
// Kernel 3: bf16 GEMM, C = A * B^T + bias   (256x256 tile, 8-phase schedule)
//
// Round-8 change: REGISTER-LEVEL READ PIPELINING. Rounds 4-7 analysis: LDS
// reads (2311 cyc/tile/CU) and MFMA (2480 cyc/tile/SIMD) were fully
// SERIALIZED by the phase structure (reads -> bar -> consuming MFMA inside
// one window) -> 5560 cyc/tile, MfmaUtil 41%. Fix: each phase issues the
// ds_reads for a FUTURE phase; its MFMA consumes registers read >=1 window
// earlier. Reads and MFMA now overlap across the barrier (different pipes,
// no data dependency, all compiler-visible).
//   Read schedule:  P0: bvHi(t)[4]  P1: avHi(t)[8]  P2: avLo(t+1)[8]
//                   P3: bvLo(t+1)[4]   (into ping-pong bvLo arrays)
//   MFMA schedule:  P0: Q00=avLo*bvLoC  P1: Q01=avLo*bvHi
//                   P2: Q11=avHi*bvHi   P3: Q10=avHi*bvLoC
//   Stage schedule (unchanged): P0: A-hi(t+1), P1: A-lo(t+2),
//                   P2: B-lo(t+2), P3: B-hi(t+2)
//   vmcnt(6) at P1 AND P3 (counted, never 0). Ledger (FIFO-checked):
//   - P1(t) vmcnt: 10 outstanding -> confirms A-lo(t+1),B-lo(t+1); +bar#1
//     precedes their reads at P2(t)/P3(t).
//   - P3(t) vmcnt: 10 -> confirms B-hi(t+1),A-hi(t+1); +bar#1 precedes
//     their reads at P0(t+1)/P1(t+1).
//   - Region overwrite vs last read: A-lo read P2(t-1) < stage P1(t);
//     B-lo read P3(t-1) < P2(t); B-hi read P0(t) < P3(t); A-hi read
//     P1(t-1) < P0(t) (other parity). All >=1 barrier apart.
//
// LDS (128 KiB): 2 dbuf x { A-lo@0, A-hi@16384, B-lo@32768, B-hi@49152 }.
// XOR involution swizzle (round-2-proven, 0 conflicts).
// ---------------------------------------------------------------------------
#define STAGE(gbase, eoff, loff)                                              \
    __builtin_amdgcn_global_load_lds(                                         \
        (const __attribute__((address_space(1))) void*)((gbase) + (eoff)),    \
        (__attribute__((address_space(3))) void*)(lds + (loff)), 16, 0, 0)

__device__ __forceinline__ void mfma_quad(
    f32x4 (&accq)[4][2], bf16x8 (&av)[4][2], bf16x8 (&bv)[2][2])
{
    __builtin_amdgcn_s_setprio(1);
#pragma unroll
    for (int ks = 0; ks < 2; ++ks)
#pragma unroll
        for (int m = 0; m < 4; ++m)
#pragma unroll
            for (int n = 0; n < 2; ++n)
                accq[m][n] = __builtin_amdgcn_mfma_f32_16x16x32_bf16(
                    av[m][ks], bv[n][ks], accq[m][n], 0, 0, 0);
    __builtin_amdgcn_s_setprio(0);
}

template<int BUF>
__device__ __forceinline__ void tile_body(
    int t, f32x4 (&acc)[4][4][2],
    const __hip_bfloat16* __restrict__ A, const __hip_bfloat16* __restrict__ B,
    char* lds,
    const int (&sA_lo)[2], const int (&sA_hi)[2],
    const int (&sB_lo)[2], const int (&sB_hi)[2],
    int dst0, int dst1,
    const char* pA0, const char* pA1, const char* pB0, const char* pB1,
    bf16x8 (&avLo)[4][2], bf16x8 (&avHi)[4][2], bf16x8 (&bvHi)[2][2],
    bf16x8 (&bvLoC)[2][2], bf16x8 (&bvLoN)[2][2])
{
    constexpr int LB  = BUF * 65536;         // this tile's buffer
    constexpr int LB1 = (BUF ^ 1) * 65536;   // (t+1)'s buffer
    const int koff1 = ((t + 1) & (NT - 1)) * 64;   // wave-uniform (SALU)
    const int koff2 = ((t + 2) & (NT - 1)) * 64;

    // ---- P0: read bvHi(t) [future: used P1,P2]; stage A-hi(t+1);
    //      MFMA Q(0,0) = avLo(t) x bvLoC(t)  (regs read in prev windows) ----
#pragma unroll
    for (int n = 0; n < 2; ++n) {
        bvHi[n][0] = *(const bf16x8*)(pB0 + LB + 16384 + n * 2048);
        bvHi[n][1] = *(const bf16x8*)(pB1 + LB + 16384 + n * 2048);
    }
    STAGE(A, sA_hi[0] + koff1, LB1 + 16384 + dst0);
    STAGE(A, sA_hi[1] + koff1, LB1 + 16384 + dst1);
    __builtin_amdgcn_s_barrier();
    mfma_quad(acc[0], avLo, bvLoC);
    __builtin_amdgcn_s_barrier();

    // ---- P1: read avHi(t) [used P2,P3]; stage A-lo(t+2); vmcnt(6):
    //      confirms A-lo(t+1),B-lo(t+1); MFMA Q(0,1) = avLo x bvHi ----
#pragma unroll
    for (int m = 0; m < 4; ++m) {
        avHi[m][0] = *(const bf16x8*)(pA0 + LB + 16384 + m * 2048);
        avHi[m][1] = *(const bf16x8*)(pA1 + LB + 16384 + m * 2048);
    }
    STAGE(A, sA_lo[0] + koff2, LB + dst0);
    STAGE(A, sA_lo[1] + koff2, LB + dst1);
    asm volatile("s_waitcnt vmcnt(6)" ::: "memory");
    __builtin_amdgcn_s_barrier();
    mfma_quad(acc[1], avLo, bvHi);
    __builtin_amdgcn_s_barrier();

    // ---- P2: read avLo(t+1) from other buffer [used P0,P1 of t+1];
    //      stage B-lo(t+2); MFMA Q(1,1) = avHi x bvHi ----
#pragma unroll
    for (int m = 0; m < 4; ++m) {
        avLo[m][0] = *(const bf16x8*)(pA0 + LB1 + m * 2048);
        avLo[m][1] = *(const bf16x8*)(pA1 + LB1 + m * 2048);
    }
    STAGE(B, sB_lo[0] + koff2, LB + 32768 + dst0);
    STAGE(B, sB_lo[1] + koff2, LB + 32768 + dst1);
    __builtin_amdgcn_s_barrier();
    mfma_quad(acc[2], avHi, bvHi);
    __builtin_amdgcn_s_barrier();

    // ---- P3: read bvLo(t+1) into ping-pong NEXT array; stage B-hi(t+2);
    //      vmcnt(6): confirms B-hi(t+1),A-hi(t+1);
    //      MFMA Q(1,0) = avHi x bvLoC ----
#pragma unroll
    for (int n = 0; n < 2; ++n) {
        bvLoN[n][0] = *(const bf16x8*)(pB0 + LB1 + n * 2048);
        bvLoN[n][1] = *(const bf16x8*)(pB1 + LB1 + n * 2048);
    }
    STAGE(B, sB_hi[0] + koff2, LB + 49152 + dst0);
    STAGE(B, sB_hi[1] + koff2, LB + 49152 + dst1);
    asm volatile("s_waitcnt vmcnt(6)" ::: "memory");
    __builtin_amdgcn_s_barrier();
    mfma_quad(acc[3], avHi, bvLoC);
    __builtin_amdgcn_s_barrier();
}

__global__ __launch_bounds__(512, 2) void gemm_bf16_8phase(
    const __hip_bfloat16* __restrict__ A, const __hip_bfloat16* __restrict__ B,
    const float* __restrict__ bias, float* __restrict__ C)
{
    extern __shared__ char lds[];  // 131072 B

    const int tid = threadIdx.x;
    const int lane = tid & 63;
    const int wid = tid >> 6;       // 0..7
    const int wr = wid >> 2;        // 0..1 (M split)
    const int wc = wid & 3;         // 0..3 (N split)
    const int l15 = lane & 15;
    const int kgrp = lane >> 4;

    // XCD-aware bijective swizzle; consecutive same-XCD blocks share tile_n.
    const int wg = blockIdx.x;
    const int swz = (wg & 7) * (NWG / 8) + (wg >> 3);
    const int tile_m = swz % TILES_M;
    const int tile_n = swz / TILES_M;
    const int m0 = tile_m * BM;
    const int n0 = tile_n * BN;

    // ---- Precomputed stage-source element offsets (per lane, once) ----
    int sA_lo[2], sA_hi[2], sB_lo[2], sB_hi[2];
#pragma unroll
    for (int c = 0; c < 2; ++c) {
        const int idx = c * 512 + tid;          // 0..1023 chunk id (linear LDS)
        const int row = idx >> 3;               // 0..127
        const int scol = (idx & 7) ^ (row & 7); // pre-swizzled source chunk
        sA_lo[c] = (m0 + row) * K_DIM + scol * 8;
        sA_hi[c] = sA_lo[c] + 128 * K_DIM;
        sB_lo[c] = (n0 + row) * K_DIM + scol * 8;
        sB_hi[c] = sB_lo[c] + 128 * K_DIM;
    }
    const int dst0 = wid * 1024;          // (c*512 + wid*64)*16, c=0
    const int dst1 = 8192 + wid * 1024;   // c=1

    // ---- Precomputed fragment-read base pointers (buf0; buf1 = +65536) ----
    const int xlo = l15 & 7;
    const char* pA0 = lds + (wr * 64 + l15) * 128 + ((kgrp) ^ xlo) * 16;
    const char* pA1 = lds + (wr * 64 + l15) * 128 + ((4 + kgrp) ^ xlo) * 16;
    const char* pB0 = lds + 32768 + (wc * 32 + l15) * 128 + ((kgrp) ^ xlo) * 16;
    const char* pB1 = lds + 32768 + (wc * 32 + l15) * 128 + ((4 + kgrp) ^ xlo) * 16;

    // acc quadrants: 0=(0,0) 1=(0,1) 2=(1,1) 3=(1,0)  (mq,nq)
    f32x4 acc[4][4][2];
#pragma unroll
    for (int q = 0; q < 4; ++q)
#pragma unroll
        for (int m = 0; m < 4; ++m)
#pragma unroll
            for (int n = 0; n < 2; ++n)
                acc[q][m][n] = (f32x4){0.f, 0.f, 0.f, 0.f};

    // Fragment registers (live across tile_body calls)
    bf16x8 avLo[4][2], avHi[4][2], bvHi[2][2], bvLoA[2][2], bvLoB[2][2];

    // Prologue: 7 halves, FIFO order matching steady state:
    // A-lo(0), B-lo(0), B-hi(0), A-hi(0), A-lo(1), B-lo(1), B-hi(1)
    STAGE(A, sA_lo[0], dst0);                 STAGE(A, sA_lo[1], dst1);
    STAGE(B, sB_lo[0], 32768 + dst0);         STAGE(B, sB_lo[1], 32768 + dst1);
    STAGE(B, sB_hi[0], 49152 + dst0);         STAGE(B, sB_hi[1], 49152 + dst1);
    STAGE(A, sA_hi[0], 16384 + dst0);         STAGE(A, sA_hi[1], 16384 + dst1);
    STAGE(A, sA_lo[0] + 64, 65536 + dst0);    STAGE(A, sA_lo[1] + 64, 65536 + dst1);
    STAGE(B, sB_lo[0] + 64, 98304 + dst0);    STAGE(B, sB_lo[1] + 64, 98304 + dst1);
    STAGE(B, sB_hi[0] + 64, 114688 + dst0);   STAGE(B, sB_hi[1] + 64, 114688 + dst1);
    asm volatile("s_waitcnt vmcnt(6)" ::: "memory"); // tile-0's 4 halves landed
    __builtin_amdgcn_s_barrier();

    // Prologue prefetch-reads (the P2(-1)/P3(-1) slots): avLo(0), bvLoA(0)
#pragma unroll
    for (int m = 0; m < 4; ++m) {
        avLo[m][0] = *(const bf16x8*)(pA0 + m * 2048);
        avLo[m][1] = *(const bf16x8*)(pA1 + m * 2048);
    }
#pragma unroll
    for (int n = 0; n < 2; ++n) {
        bvLoA[n][0] = *(const bf16x8*)(pB0 + n * 2048);
        bvLoA[n][1] = *(const bf16x8*)(pB1 + n * 2048);
    }

    for (int t = 0; t < NT; t += 2) {
        tile_body<0>(t,     acc, A, B, lds, sA_lo, sA_hi, sB_lo, sB_hi,
                     dst0, dst1, pA0, pA1, pB0, pB1,
                     avLo, avHi, bvHi, bvLoA, bvLoB);
        tile_body<1>(t + 1, acc, A, B, lds, sA_lo, sA_hi, sB_lo, sB_hi,
                     dst0, dst1, pA0, pA1, pB0, pB1,
                     avLo, avHi, bvHi, bvLoB, bvLoA);
    }

    // Epilogue (C/D layout: col = lane&15, row = (lane>>4)*4 + reg).
#pragma unroll
    for (int q = 0; q < 4; ++q) {
        const int mqe = q >> 1;
        const int nqe = (q == 1 || q == 2) ? 1 : 0;
#pragma unroll
        for (int n = 0; n < 2; ++n) {
            const int col = n0 + nqe * 128 + wc * 32 + n * 16 + l15;
            const float bval = bias[col];
#pragma unroll
            for (int m = 0; m < 4; ++m) {
                const int row = m0 + mqe * 128 + wr * 64 + m * 16 + kgrp * 4;
#pragma unroll
                for (int r = 0; r < 4; ++r)
                    __builtin_nontemporal_store(acc[q][m][n][r] + bval,
                        &C[(size_t)(row + r) * N_DIM + col]);
            }
        }
    }
}

// ---------------------------------------------------------------------------
extern "C" void kernel_launch(void* const* d_in, const int* in_sizes, int n_in,
                              void* d_out, int out_size, void* d_ws, size_t ws_size,
                              hipStream_t stream)
{
    const float* x      = (const float*)d_in[0];  // [4,2048,4096] f32
    const int*   codes  = (const int*)d_in[1];    // [704512,64] i32
    const float* absmax = (const float*)d_in[2];  // [704512] f32
    const float* bias   = (const float*)d_in[3];  // [11008] f32
    float* out = (float*)d_out;                   // [4,2048,11008] f32

    const size_t w_bytes = (size_t)N_DIM * K_DIM * sizeof(__hip_bfloat16);
    const size_t x_bytes = (size_t)M_DIM * K_DIM * sizeof(__hip_bfloat16);
    if (ws_size < w_bytes + x_bytes) {
        fprintf(stderr, "kernel_launch: ws_size=%zu < needed %zu\n",
                ws_size, w_bytes + x_bytes);
        return;
    }
    __hip_bfloat16* wbf = (__hip_bfloat16*)d_ws;
    __hip_bfloat16* xbf = (__hip_bfloat16*)((char*)d_ws + w_bytes);

    // Allow 128 KiB dynamic LDS (idempotent host-side call; capture-safe).
    hipFuncSetAttribute((const void*)gemm_bf16_8phase,
                        hipFuncAttributeMaxDynamicSharedMemorySize, 131072);

    fp4_dequant_kernel<<<dim3(22016), dim3(256), 0, stream>>>(codes, absmax, wbf);
    f32_to_bf16_kernel<<<dim3(16384), dim3(256), 0, stream>>>(x, xbf);
    gemm_bf16_8phase<<<dim3(NWG), dim3(512), 131072, stream>>>(xbf, wbf, bias, out);
}

// Round 9
// 730.902 us; speedup vs baseline: 1.1432x; 1.1386x over previous
//
#include <hip/hip_runtime.h>
#include <hip/hip_bf16.h>
#include <stdint.h>
#include <stdio.h>

// Problem geometry (fixed by the reference)
#define M_DIM 8192    // 4*2048
#define K_DIM 4096    // IN_FEATURES
#define N_DIM 11008   // OUT_FEATURES

// 256^2 8-phase template (m201 structure)
#define BM 256
#define BN 256
#define BK 64
#define NT (K_DIM / BK)           // 64 K-tiles (power of 2 -> & wrap ok)
#define TILES_M (M_DIM / BM)      // 32
#define TILES_N (N_DIM / BN)      // 43
#define NWG (TILES_M * TILES_N)   // 1376 (%8==0 -> simple XCD swizzle bijective)

typedef __bf16 bf16x8 __attribute__((ext_vector_type(8)));
typedef float f32x4 __attribute__((ext_vector_type(4)));

__device__ __constant__ float kFp4Code[16] = {
    0.0f,           0.0052083333f,  0.6666666666f, 1.0f,
    0.3333333333f,  0.5f,           0.1666666666f, 0.25f,
    -0.0f,          -0.0052083333f, -0.6666666666f, -1.0f,
    -0.3333333333f, -0.5f,          -0.1666666666f, -0.25f
};

// ---------------------------------------------------------------------------
// Kernel 1: FP4 dequant -> bf16 W [N_DIM][K_DIM]
// ---------------------------------------------------------------------------
__global__ __launch_bounds__(256) void fp4_dequant_kernel(
    const int* __restrict__ codes, const float* __restrict__ absmax,
    __hip_bfloat16* __restrict__ w)
{
    __shared__ float lut[16];
    if (threadIdx.x < 16) lut[threadIdx.x] = kFp4Code[threadIdx.x];
    __syncthreads();

    const int t = blockIdx.x * 256 + threadIdx.x;  // < 5,636,096
    const int4* cp = (const int4*)codes;
    const int4 c0 = cp[2 * t];
    const int4 c1 = cp[2 * t + 1];
    const float am = absmax[t >> 3];

    union { int4 v; __hip_bfloat16 h[8]; } u;
    u.h[0] = __float2bfloat16(lut[c0.x & 15] * am);
    u.h[1] = __float2bfloat16(lut[c0.y & 15] * am);
    u.h[2] = __float2bfloat16(lut[c0.z & 15] * am);
    u.h[3] = __float2bfloat16(lut[c0.w & 15] * am);
    u.h[4] = __float2bfloat16(lut[c1.x & 15] * am);
    u.h[5] = __float2bfloat16(lut[c1.y & 15] * am);
    u.h[6] = __float2bfloat16(lut[c1.z & 15] * am);
    u.h[7] = __float2bfloat16(lut[c1.w & 15] * am);
    ((int4*)w)[t] = u.v;
}

// ---------------------------------------------------------------------------
// Kernel 2: x fp32 -> bf16  [M_DIM][K_DIM]
// ---------------------------------------------------------------------------
__global__ __launch_bounds__(256) void f32_to_bf16_kernel(
    const float* __restrict__ x, __hip_bfloat16* __restrict__ y)
{
    const int t = blockIdx.x * 256 + threadIdx.x;  // < 4,194,304
    const float4* xp = (const float4*)x;
    const float4 a = xp[2 * t];
    const float4 b = xp[2 * t + 1];
    union { int4 v; __hip_bfloat16 h[8]; } u;
    u.h[0] = __float2bfloat16(a.x);
    u.h[1] = __float2bfloat16(a.y);
    u.h[2] = __float2bfloat16(a.z);
    u.h[3] = __float2bfloat16(a.w);
    u.h[4] = __float2bfloat16(b.x);
    u.h[5] = __float2bfloat16(b.y);
    u.h[6] = __float2bfloat16(b.z);
    u.h[7] = __float2bfloat16(b.w);
    ((int4*)y)[t] = u.v;
}

// ---------------------------------------------------------------------------
// Kernel 3: bf16 GEMM, C = A * B^T + bias   (256x256 tile, 8-phase schedule)
//
// Round-9 change vs round-8: 2D BRICK WORK ORDERING ONLY (kernel body
// byte-identical). Theory: rounds 5-8 nulls (window pinned at 1390 cyc,
// MfmaUtil 41% under 4 different schedules) => supply-side limit. Staged
// volume = 5.7 GB/dispatch; old column order (tile_m fast within an XCD)
// gives ZERO A-sharing among the 32 concurrent blocks of an XCD: per K-tile
// each XCD pulls 1.06 MB of L2-misses (32 distinct A slabs + 1 B slab).
// New order: each XCD's concurrent 32 blocks form an 8(tile_m) x 4(tile_n)
// rectangle -> per-K-tile footprint 384 KB (A shared 4-way, B 8-way),
// ~2.7x less L3 traffic. 43 tile_n is prime -> ragged groups: 10 groups of
// width 4 (128 tiles each, 8x4 bricks) + 1 group of width 3.
//   s = XCD-striped index (172 consecutive s per XCD, bijective);
//   s < 1280: g = s>>7, j = s&127, bm = j>>2, bn = g*4 + (j&3)
//   s >= 1280: j = s-1280, bm = j/3, bn = 40 + j%3
//
// Schedule (unchanged, round-8): reads one window ahead (P0: bvHi(t),
// P1: avHi(t), P2: avLo(t+1), P3: bvLo(t+1) ping-pong); stages P0: A-hi(t+1),
// P1: A-lo(t+2), P2: B-lo(t+2), P3: B-hi(t+2); vmcnt(6) at P1+P3 only.
// LDS (128 KiB): 2 dbuf x { A-lo@0, A-hi@16384, B-lo@32768, B-hi@49152 }.
// XOR involution swizzle (round-2-proven, 0 conflicts).
// ---------------------------------------------------------------------------
#define STAGE(gbase, eoff, loff)                                              \
    __builtin_amdgcn_global_load_lds(                                         \
        (const __attribute__((address_space(1))) void*)((gbase) + (eoff)),    \
        (__attribute__((address_space(3))) void*)(lds + (loff)), 16, 0, 0)

__device__ __forceinline__ void mfma_quad(
    f32x4 (&accq)[4][2], bf16x8 (&av)[4][2], bf16x8 (&bv)[2][2])
{
    __builtin_amdgcn_s_setprio(1);
#pragma unroll
    for (int ks = 0; ks < 2; ++ks)
#pragma unroll
        for (int m = 0; m < 4; ++m)
#pragma unroll
            for (int n = 0; n < 2; ++n)
                accq[m][n] = __builtin_amdgcn_mfma_f32_16x16x32_bf16(
                    av[m][ks], bv[n][ks], accq[m][n], 0, 0, 0);
    __builtin_amdgcn_s_setprio(0);
}

template<int BUF>
__device__ __forceinline__ void tile_body(
    int t, f32x4 (&acc)[4][4][2],
    const __hip_bfloat16* __restrict__ A, const __hip_bfloat16* __restrict__ B,
    char* lds,
    const int (&sA_lo)[2], const int (&sA_hi)[2],
    const int (&sB_lo)[2], const int (&sB_hi)[2],
    int dst0, int dst1,
    const char* pA0, const char* pA1, const char* pB0, const char* pB1,
    bf16x8 (&avLo)[4][2], bf16x8 (&avHi)[4][2], bf16x8 (&bvHi)[2][2],
    bf16x8 (&bvLoC)[2][2], bf16x8 (&bvLoN)[2][2])
{
    constexpr int LB  = BUF * 65536;         // this tile's buffer
    constexpr int LB1 = (BUF ^ 1) * 65536;   // (t+1)'s buffer
    const int koff1 = ((t + 1) & (NT - 1)) * 64;   // wave-uniform (SALU)
    const int koff2 = ((t + 2) & (NT - 1)) * 64;

    // ---- P0: read bvHi(t) [used P1,P2]; stage A-hi(t+1);
    //      MFMA Q(0,0) = avLo(t) x bvLoC(t) (regs read in prev windows) ----
#pragma unroll
    for (int n = 0; n < 2; ++n) {
        bvHi[n][0] = *(const bf16x8*)(pB0 + LB + 16384 + n * 2048);
        bvHi[n][1] = *(const bf16x8*)(pB1 + LB + 16384 + n * 2048);
    }
    STAGE(A, sA_hi[0] + koff1, LB1 + 16384 + dst0);
    STAGE(A, sA_hi[1] + koff1, LB1 + 16384 + dst1);
    __builtin_amdgcn_s_barrier();
    mfma_quad(acc[0], avLo, bvLoC);
    __builtin_amdgcn_s_barrier();

    // ---- P1: read avHi(t) [used P2,P3]; stage A-lo(t+2); vmcnt(6):
    //      confirms A-lo(t+1),B-lo(t+1); MFMA Q(0,1) = avLo x bvHi ----
#pragma unroll
    for (int m = 0; m < 4; ++m) {
        avHi[m][0] = *(const bf16x8*)(pA0 + LB + 16384 + m * 2048);
        avHi[m][1] = *(const bf16x8*)(pA1 + LB + 16384 + m * 2048);
    }
    STAGE(A, sA_lo[0] + koff2, LB + dst0);
    STAGE(A, sA_lo[1] + koff2, LB + dst1);
    asm volatile("s_waitcnt vmcnt(6)" ::: "memory");
    __builtin_amdgcn_s_barrier();
    mfma_quad(acc[1], avLo, bvHi);
    __builtin_amdgcn_s_barrier();

    // ---- P2: read avLo(t+1) from other buffer [used P0,P1 of t+1];
    //      stage B-lo(t+2); MFMA Q(1,1) = avHi x bvHi ----
#pragma unroll
    for (int m = 0; m < 4; ++m) {
        avLo[m][0] = *(const bf16x8*)(pA0 + LB1 + m * 2048);
        avLo[m][1] = *(const bf16x8*)(pA1 + LB1 + m * 2048);
    }
    STAGE(B, sB_lo[0] + koff2, LB + 32768 + dst0);
    STAGE(B, sB_lo[1] + koff2, LB + 32768 + dst1);
    __builtin_amdgcn_s_barrier();
    mfma_quad(acc[2], avHi, bvHi);
    __builtin_amdgcn_s_barrier();

    // ---- P3: read bvLo(t+1) into ping-pong NEXT array; stage B-hi(t+2);
    //      vmcnt(6): confirms B-hi(t+1),A-hi(t+1);
    //      MFMA Q(1,0) = avHi x bvLoC ----
#pragma unroll
    for (int n = 0; n < 2; ++n) {
        bvLoN[n][0] = *(const bf16x8*)(pB0 + LB1 + n * 2048);
        bvLoN[n][1] = *(const bf16x8*)(pB1 + LB1 + n * 2048);
    }
    STAGE(B, sB_hi[0] + koff2, LB + 49152 + dst0);
    STAGE(B, sB_hi[1] + koff2, LB + 49152 + dst1);
    asm volatile("s_waitcnt vmcnt(6)" ::: "memory");
    __builtin_amdgcn_s_barrier();
    mfma_quad(acc[3], avHi, bvLoC);
    __builtin_amdgcn_s_barrier();
}

__global__ __launch_bounds__(512, 2) void gemm_bf16_8phase(
    const __hip_bfloat16* __restrict__ A, const __hip_bfloat16* __restrict__ B,
    const float* __restrict__ bias, float* __restrict__ C)
{
    extern __shared__ char lds[];  // 131072 B

    const int tid = threadIdx.x;
    const int lane = tid & 63;
    const int wid = tid >> 6;       // 0..7
    const int wr = wid >> 2;        // 0..1 (M split)
    const int wc = wid & 3;         // 0..3 (N split)
    const int l15 = lane & 15;
    const int kgrp = lane >> 4;

    // XCD stripe (bijective) + 2D brick order: each XCD's 32 concurrent
    // blocks form ~8(tile_m) x 4(tile_n) -> A slabs shared 4-way, B 8-way.
    const int wg = blockIdx.x;
    const int s = (wg & 7) * (NWG / 8) + (wg >> 3);
    int bm, bn;
    if (s < 1280) {                 // 10 groups of width 4 (8x4 bricks)
        const int g = s >> 7;       // group id
        const int j = s & 127;
        bm = j >> 2;
        bn = g * 4 + (j & 3);
    } else {                        // last group: width 3
        const int j = s - 1280;     // 0..95
        bm = j / 3;
        bn = 40 + j % 3;
    }
    const int m0 = bm * BM;
    const int n0 = bn * BN;

    // ---- Precomputed stage-source element offsets (per lane, once) ----
    int sA_lo[2], sA_hi[2], sB_lo[2], sB_hi[2];
#pragma unroll
    for (int c = 0; c < 2; ++c) {
        const int idx = c * 512 + tid;          // 0..1023 chunk id (linear LDS)
        const int row = idx >> 3;               // 0..127
        const int scol = (idx & 7) ^ (row & 7); // pre-swizzled source chunk
        sA_lo[c] = (m0 + row) * K_DIM + scol * 8;
        sA_hi[c] = sA_lo[c] + 128 * K_DIM;
        sB_lo[c] = (n0 + row) * K_DIM + scol * 8;
        sB_hi[c] = sB_lo[c] + 128 * K_DIM;
    }
    const int dst0 = wid * 1024;          // (c*512 + wid*64)*16, c=0
    const int dst1 = 8192 + wid * 1024;   // c=1

    // ---- Precomputed fragment-read base pointers (buf0; buf1 = +65536) ----
    const int xlo = l15 & 7;
    const char* pA0 = lds + (wr * 64 + l15) * 128 + ((kgrp) ^ xlo) * 16;
    const char* pA1 = lds + (wr * 64 + l15) * 128 + ((4 + kgrp) ^ xlo) * 16;
    const char* pB0 = lds + 32768 + (wc * 32 + l15) * 128 + ((kgrp) ^ xlo) * 16;
    const char* pB1 = lds + 32768 + (wc * 32 + l15) * 128 + ((4 + kgrp) ^ xlo) * 16;

    // acc quadrants: 0=(0,0) 1=(0,1) 2=(1,1) 3=(1,0)  (mq,nq)
    f32x4 acc[4][4][2];
#pragma unroll
    for (int q = 0; q < 4; ++q)
#pragma unroll
        for (int m = 0; m < 4; ++m)
#pragma unroll
            for (int n = 0; n < 2; ++n)
                acc[q][m][n] = (f32x4){0.f, 0.f, 0.f, 0.f};

    // Fragment registers (live across tile_body calls)
    bf16x8 avLo[4][2], avHi[4][2], bvHi[2][2], bvLoA[2][2], bvLoB[2][2];

    // Prologue: 7 halves, FIFO order matching steady state:
    // A-lo(0), B-lo(0), B-hi(0), A-hi(0), A-lo(1), B-lo(1), B-hi(1)
    STAGE(A, sA_lo[0], dst0);                 STAGE(A, sA_lo[1], dst1);
    STAGE(B, sB_lo[0], 32768 + dst0);         STAGE(B, sB_lo[1], 32768 + dst1);
    STAGE(B, sB_hi[0], 49152 + dst0);         STAGE(B, sB_hi[1], 49152 + dst1);
    STAGE(A, sA_hi[0], 16384 + dst0);         STAGE(A, sA_hi[1], 16384 + dst1);
    STAGE(A, sA_lo[0] + 64, 65536 + dst0);    STAGE(A, sA_lo[1] + 64, 65536 + dst1);
    STAGE(B, sB_lo[0] + 64, 98304 + dst0);    STAGE(B, sB_lo[1] + 64, 98304 + dst1);
    STAGE(B, sB_hi[0] + 64, 114688 + dst0);   STAGE(B, sB_hi[1] + 64, 114688 + dst1);
    asm volatile("s_waitcnt vmcnt(6)" ::: "memory"); // tile-0's 4 halves landed
    __builtin_amdgcn_s_barrier();

    // Prologue prefetch-reads (the P2(-1)/P3(-1) slots): avLo(0), bvLoA(0)
#pragma unroll
    for (int m = 0; m < 4; ++m) {
        avLo[m][0] = *(const bf16x8*)(pA0 + m * 2048);
        avLo[m][1] = *(const bf16x8*)(pA1 + m * 2048);
    }
#pragma unroll
    for (int n = 0; n < 2; ++n) {
        bvLoA[n][0] = *(const bf16x8*)(pB0 + n * 2048);
        bvLoA[n][1] = *(const bf16x8*)(pB1 + n * 2048);
    }

    for (int t = 0; t < NT; t += 2) {
        tile_body<0>(t,     acc, A, B, lds, sA_lo, sA_hi, sB_lo, sB_hi,
                     dst0, dst1, pA0, pA1, pB0, pB1,
                     avLo, avHi, bvHi, bvLoA, bvLoB);
        tile_body<1>(t + 1, acc, A, B, lds, sA_lo, sA_hi, sB_lo, sB_hi,
                     dst0, dst1, pA0, pA1, pB0, pB1,
                     avLo, avHi, bvHi, bvLoB, bvLoA);
    }

    // Epilogue (C/D layout: col = lane&15, row = (lane>>4)*4 + reg).
#pragma unroll
    for (int q = 0; q < 4; ++q) {
        const int mqe = q >> 1;
        const int nqe = (q == 1 || q == 2) ? 1 : 0;
#pragma unroll
        for (int n = 0; n < 2; ++n) {
            const int col = n0 + nqe * 128 + wc * 32 + n * 16 + l15;
            const float bval = bias[col];
#pragma unroll
            for (int m = 0; m < 4; ++m) {
                const int row = m0 + mqe * 128 + wr * 64 + m * 16 + kgrp * 4;
#pragma unroll
                for (int r = 0; r < 4; ++r)
                    __builtin_nontemporal_store(acc[q][m][n][r] + bval,
                        &C[(size_t)(row + r) * N_DIM + col]);
            }
        }
    }
}

// ---------------------------------------------------------------------------
extern "C" void kernel_launch(void* const* d_in, const int* in_sizes, int n_in,
                              void* d_out, int out_size, void* d_ws, size_t ws_size,
                              hipStream_t stream)
{
    const float* x      = (const float*)d_in[0];  // [4,2048,4096] f32
    const int*   codes  = (const int*)d_in[1];    // [704512,64] i32
    const float* absmax = (const float*)d_in[2];  // [704512] f32
    const float* bias   = (const float*)d_in[3];  // [11008] f32
    float* out = (float*)d_out;                   // [4,2048,11008] f32

    const size_t w_bytes = (size_t)N_DIM * K_DIM * sizeof(__hip_bfloat16);
    const size_t x_bytes = (size_t)M_DIM * K_DIM * sizeof(__hip_bfloat16);
    if (ws_size < w_bytes + x_bytes) {
        fprintf(stderr, "kernel_launch: ws_size=%zu < needed %zu\n",
                ws_size, w_bytes + x_bytes);
        return;
    }
    __hip_bfloat16* wbf = (__hip_bfloat16*)d_ws;
    __hip_bfloat16* xbf = (__hip_bfloat16*)((char*)d_ws + w_bytes);

    // Allow 128 KiB dynamic LDS (idempotent host-side call; capture-safe).
    hipFuncSetAttribute((const void*)gemm_bf16_8phase,
                        hipFuncAttributeMaxDynamicSharedMemorySize, 131072);

    fp4_dequant_kernel<<<dim3(22016), dim3(256), 0, stream>>>(codes, absmax, wbf);
    f32_to_bf16_kernel<<<dim3(16384), dim3(256), 0, stream>>>(x, xbf);
    gemm_bf16_8phase<<<dim3(NWG), dim3(512), 131072, stream>>>(xbf, wbf, bias, out);
}